// Round 9
// baseline (114.849 us; speedup 1.0000x reference)
//
#include <hip/hip_runtime.h>
#include <hip/hip_bf16.h>

// MMD-RBF: B=4, Ns=Nt=2048 (N=4096 concat), K=32, KERNEL_MUL=2, KERNEL_NUM=5.
// Pass 1: per-point sq-norms, hi/lo bf16 fragment precompute (if ws fits),
//         per-block partial {sum_sq, comp sums}; zero quadbuf+cnt
// Pass 2: 1 block: reduce partials -> coef[b] (widest-bandwidth exp2 coefficient)
// Pass 3: 528 upper-tri 128x128 tile pairs per batch; Gram via MFMA bf16 hi/lo
//         (2 independent 2-chains, fp32 accum); fragments from precomputed
//         buffer (or inline-built fallback); fused exp-ladder epilogue;
//         kernel-symmetry doubling; completion counter -> last block emits out[b].

#define NPTS 4096   // per batch (2048 src + 2048 tgt)
#define HALF 2048
#define KDIM 32
#define T3   128    // tile dim
#define NTB3 32     // NPTS / T3
#define NPAIR3 528  // NTB3*(NTB3+1)/2
#define SPREAD 64

#define WS_SQ    0          // 4*4096*4  = 65536
#define WS_PART  65536      // 4*16*33*8 = 16896
#define WS_QUAD  82432      // 4*4*64*8  = 8192
#define WS_CNT   90624      // 16
#define WS_COEF  90640      // 16
#define WS_FRAG  98304      // 4*4096*128 = 2 MB
#define WS_NEED  (98304 + 4 * NPTS * 128)

typedef __attribute__((ext_vector_type(8))) short short8v;  // 8 bf16 (4 VGPRs)
typedef __attribute__((ext_vector_type(4))) float f32x4;    // C/D frag

__device__ __forceinline__ float fast_exp2(float x) {
#if __has_builtin(__builtin_amdgcn_exp2f)
  return __builtin_amdgcn_exp2f(x);
#else
  return exp2f(x);
#endif
}

__device__ __forceinline__ unsigned int bf16_rne(float x) {
  unsigned int u = __float_as_uint(x);
  return (u + 0x7fffu + ((u >> 16) & 1u)) >> 16;
}

__device__ __forceinline__ const float* point_ptr(const float* __restrict__ src,
                                                  const float* __restrict__ tgt,
                                                  int b, int p) {
  return (p < HALF) ? src + ((size_t)b * HALF + p) * KDIM
                    : tgt + ((size_t)b * HALF + (p - HALF)) * KDIM;
}

// inline hi/lo fragment build (fallback path)
__device__ __forceinline__ void build_pair(const float4* __restrict__ p4,
                                           short8v& h, short8v& l) {
  const float4 v0 = p4[0], v1 = p4[1];
  const float xs[8] = {v0.x, v0.y, v0.z, v0.w, v1.x, v1.y, v1.z, v1.w};
#pragma unroll
  for (int e = 0; e < 8; ++e) {
    const float x = xs[e];
    const unsigned int hb = bf16_rne(x);
    const float hf = __uint_as_float(hb << 16);
    const unsigned int lb = bf16_rne(x - hf);
    h[e] = (short)hb;
    l[e] = (short)lb;
  }
}

// ---- Pass 1 ----------------------------------------------------------------
__global__ void mmd_pass1(const float* __restrict__ src, const float* __restrict__ tgt,
                          float* __restrict__ sqArr, double* __restrict__ part1,
                          double* __restrict__ quadbuf, unsigned int* __restrict__ cnt,
                          unsigned char* __restrict__ frags, int preFlag) {
  const int b = blockIdx.y;
  const int p = blockIdx.x * 256 + threadIdx.x;

  if (blockIdx.x == 0) {
    quadbuf[b * 4 * SPREAD + threadIdx.x] = 0.0;
    if (threadIdx.x == 0) cnt[b] = 0u;
  }

  const float* __restrict__ xp = point_ptr(src, tgt, b, p);
  float x[KDIM];
#pragma unroll
  for (int q = 0; q < 8; ++q) {
    float4 v = reinterpret_cast<const float4*>(xp)[q];
    x[4*q+0] = v.x; x[4*q+1] = v.y; x[4*q+2] = v.z; x[4*q+3] = v.w;
  }
  float s0 = 0.f, s1 = 0.f, s2 = 0.f, s3 = 0.f;
#pragma unroll
  for (int q = 0; q < 8; ++q) {
    s0 = fmaf(x[4*q+0], x[4*q+0], s0);
    s1 = fmaf(x[4*q+1], x[4*q+1], s1);
    s2 = fmaf(x[4*q+2], x[4*q+2], s2);
    s3 = fmaf(x[4*q+3], x[4*q+3], s3);
  }
  float sq = (s0 + s1) + (s2 + s3);
  sqArr[(size_t)b * NPTS + p] = sq;

  // precompute hi/lo bf16 fragments: 64 B hi + 64 B lo per point
  if (preFlag) {
    unsigned int hw[16], lw[16];
#pragma unroll
    for (int e = 0; e < 16; ++e) {
      const float xa = x[2*e], xb = x[2*e+1];
      const unsigned int ha = bf16_rne(xa);
      const unsigned int la = bf16_rne(xa - __uint_as_float(ha << 16));
      const unsigned int hb = bf16_rne(xb);
      const unsigned int lb = bf16_rne(xb - __uint_as_float(hb << 16));
      hw[e] = ha | (hb << 16);
      lw[e] = la | (lb << 16);
    }
    uint4* dst = reinterpret_cast<uint4*>(frags + (size_t)(b * NPTS + p) * 128);
#pragma unroll
    for (int c = 0; c < 4; ++c)
      dst[c] = make_uint4(hw[4*c], hw[4*c+1], hw[4*c+2], hw[4*c+3]);
#pragma unroll
    for (int c = 0; c < 4; ++c)
      dst[4 + c] = make_uint4(lw[4*c], lw[4*c+1], lw[4*c+2], lw[4*c+3]);
  }

  __shared__ float lx[256][KDIM + 1];
  __shared__ float part[8][KDIM];
  __shared__ float sqpart[4];

#pragma unroll
  for (int k = 0; k < KDIM; ++k) lx[threadIdx.x][k] = x[k];

  float w = sq;
#pragma unroll
  for (int off = 32; off > 0; off >>= 1) w += __shfl_down(w, off, 64);
  if ((threadIdx.x & 63) == 0) sqpart[threadIdx.x >> 6] = w;
  __syncthreads();

  const int k = threadIdx.x & 31, g = threadIdx.x >> 5;
  float ps = 0.f;
#pragma unroll 8
  for (int r = 0; r < 32; ++r) ps += lx[g * 32 + r][k];
  part[g][k] = ps;
  __syncthreads();

  double* slot = part1 + ((size_t)b * 16 + blockIdx.x) * 33;
  if (threadIdx.x < 32) {
    float tot = 0.f;
#pragma unroll
    for (int gg = 0; gg < 8; ++gg) tot += part[gg][threadIdx.x];
    slot[1 + threadIdx.x] = (double)tot;
  }
  if (threadIdx.x == 63)
    slot[0] = (double)(sqpart[0] + sqpart[1] + sqpart[2] + sqpart[3]);
}

// ---- Pass 2: 1 block, bandwidth coefficient per batch ----------------------
__global__ void mmd_pass2(const double* __restrict__ part1, float* __restrict__ coef) {
  const int b = threadIdx.x >> 6;   // 4 waves, one per batch
  const int lane = threadIdx.x & 63;
  __shared__ double red[4][33];
  if (lane < 33) {
    double s = 0.0;
    for (int blk = 0; blk < 16; ++blk) s += part1[((size_t)b * 16 + blk) * 33 + lane];
    red[b][lane] = s;
  }
  __syncthreads();
  if (lane == 0) {
    double ssq = red[b][0], s2 = 0.0;
    for (int k = 1; k <= 32; ++k) s2 += red[b][k] * red[b][k];
    const double N = (double)NPTS;
    double bw = (2.0 * N * ssq - 2.0 * s2) / (N * N - N + 1e-8);
    bw *= 0.25;  // / KERNEL_MUL^(KERNEL_NUM//2)
    coef[b] = (float)(-1.4426950408889634 / (bw * 16.0));  // widest bandwidth (t=4)
  }
}

// ---- Pass 3: MFMA Gram + fused epilogue, upper-tri, sym-doubled ------------
template <bool PRE>
__global__ void __launch_bounds__(256, 4)
mmd_pass3(const float* __restrict__ src, const float* __restrict__ tgt,
          const float* __restrict__ sqArr, const float* __restrict__ coef,
          const unsigned char* __restrict__ frags,
          double* __restrict__ quadbuf, unsigned int* __restrict__ cnt,
          float* __restrict__ out) {
  const int t = blockIdx.x;            // 0..527 upper-tri pair index
  const int b = blockIdx.y;
  int by = (int)((sqrtf((float)(8 * t + 1)) - 1.0f) * 0.5f);
  while ((by + 1) * (by + 2) / 2 <= t) ++by;
  while (by * (by + 1) / 2 > t) --by;
  const int bx = t - by * (by + 1) / 2;

  const int tid = threadIdx.x;         // 256 = 4 waves
  const int lane = tid & 63;
  const int w = tid >> 6;
  const int lm = lane & 15;            // matrix index within 16
  const int lk = lane >> 4;            // k-group 0..3

  __shared__ double wsum[4];
  __shared__ unsigned int s_last;

  const float nc4 = coef[b];           // broadcast load (pass2 result)

  // wave region: 64x64 of the 128x128 tile
  const int rowbase = bx * T3 + (w & 1) * 64;
  const int colbase = by * T3 + (w >> 1) * 64;
  const float* __restrict__ sqA = sqArr + (size_t)b * NPTS;

  // cache B fragments (4 col-groups x hi/lo) + sq_j
  short8v Bh[4], Bl[4];
  float sqj[4];
#pragma unroll
  for (int cg = 0; cg < 4; ++cg) {
    const int p = colbase + cg * 16 + lm;
    if constexpr (PRE) {
      const unsigned char* fb = frags + (size_t)(b * NPTS + p) * 128;
      Bh[cg] = *reinterpret_cast<const short8v*>(fb + lk * 16);
      Bl[cg] = *reinterpret_cast<const short8v*>(fb + 64 + lk * 16);
    } else {
      const float* cp = point_ptr(src, tgt, b, p);
      build_pair(reinterpret_cast<const float4*>(cp) + lk * 2, Bh[cg], Bl[cg]);
    }
    sqj[cg] = sqA[p];
  }

  double accd = 0.0;
#pragma unroll
  for (int rg = 0; rg < 4; ++rg) {
    short8v Ah, Al;
    const int pa = rowbase + rg * 16 + lm;
    if constexpr (PRE) {
      const unsigned char* fa = frags + (size_t)(b * NPTS + pa) * 128;
      Ah = *reinterpret_cast<const short8v*>(fa + lk * 16);
      Al = *reinterpret_cast<const short8v*>(fa + 64 + lk * 16);
    } else {
      const float* rp = point_ptr(src, tgt, b, pa);
      build_pair(reinterpret_cast<const float4*>(rp) + lk * 2, Ah, Al);
    }
    const float4 sqi4 = *reinterpret_cast<const float4*>(sqA + rowbase + rg * 16 + lk * 4);
    const float sqi[4] = {sqi4.x, sqi4.y, sqi4.z, sqi4.w};
#pragma unroll
    for (int cg = 0; cg < 4; ++cg) {
      // two independent 2-chains: (hh+ll) and (hl+lh)
      f32x4 accP = {0.f, 0.f, 0.f, 0.f};
      f32x4 accQ = {0.f, 0.f, 0.f, 0.f};
      accP = __builtin_amdgcn_mfma_f32_16x16x32_bf16(Ah, Bh[cg], accP, 0, 0, 0);
      accQ = __builtin_amdgcn_mfma_f32_16x16x32_bf16(Ah, Bl[cg], accQ, 0, 0, 0);
      accP = __builtin_amdgcn_mfma_f32_16x16x32_bf16(Al, Bl[cg], accP, 0, 0, 0);
      accQ = __builtin_amdgcn_mfma_f32_16x16x32_bf16(Al, Bh[cg], accQ, 0, 0, 0);
      // epilogue: C lane map: col = lane&15, row = lk*4 + reg
      float rs = 0.f;
#pragma unroll
      for (int reg = 0; reg < 4; ++reg) {
        const float dot = accP[reg] + accQ[reg];
        const float L2 = fmaf(-2.0f, dot, sqi[reg] + sqj[cg]);
        float e = fast_exp2(L2 * nc4);     // widest bandwidth
        float s = e;
        e *= e; s += e;                    // e3
        e *= e; s += e;                    // e2
        e *= e; s += e;                    // e1
        e *= e; s += e;                    // e0
        rs += s;
      }
      accd += (double)rs;
    }
  }

  // block reduce (4 waves) + spread atomics
#pragma unroll
  for (int off = 32; off > 0; off >>= 1) accd += __shfl_down(accd, off, 64);
  if ((tid & 63) == 0) wsum[tid >> 6] = accd;
  __syncthreads();
  if (tid == 0) {
    const double tot = wsum[0] + wsum[1] + wsum[2] + wsum[3];
    const int rh = (bx >= NTB3 / 2) ? 1 : 0;
    const int ch = (by >= NTB3 / 2) ? 1 : 0;
    const int q  = (rh << 1) | ch;
    const int qT = (ch << 1) | rh;
    const int slot = (bx + by * NTB3) & (SPREAD - 1);
    atomicAdd(&quadbuf[(((b << 2) | q) * SPREAD) + slot], tot);
    if (bx != by)
      atomicAdd(&quadbuf[(((b << 2) | qT) * SPREAD) + slot], tot);
    __threadfence();
    s_last = atomicAdd(&cnt[b], 1u);
  }
  __syncthreads();

  // last block of this batch combines the quadrants -> out[b]
  if (s_last == NPAIR3 - 1) {
    const int qq = tid >> 6, i = tid & 63;
    double v = atomicAdd(&quadbuf[((b << 2) | qq) * SPREAD + i], 0.0);
    double sv = (qq == 0 || qq == 3) ? v : -v;
#pragma unroll
    for (int off = 32; off > 0; off >>= 1) sv += __shfl_down(sv, off, 64);
    if ((tid & 63) == 0) wsum[tid >> 6] = sv;
    __syncthreads();
    if (tid == 0) {
      const double inv = 1.0 / ((double)HALF * (double)HALF);
      out[b] = (float)((wsum[0] + wsum[1] + wsum[2] + wsum[3]) * inv);
    }
  }
}

extern "C" void kernel_launch(void* const* d_in, const int* in_sizes, int n_in,
                              void* d_out, int out_size, void* d_ws, size_t ws_size,
                              hipStream_t stream) {
  const float* src = (const float*)d_in[0];
  const float* tgt = (const float*)d_in[1];
  float* out = (float*)d_out;

  char* ws = (char*)d_ws;
  float*         sqArr   = (float*)(ws + WS_SQ);
  double*        part1   = (double*)(ws + WS_PART);
  double*        quadbuf = (double*)(ws + WS_QUAD);
  unsigned int*  cnt     = (unsigned int*)(ws + WS_CNT);
  float*         coef    = (float*)(ws + WS_COEF);
  unsigned char* frags   = (unsigned char*)(ws + WS_FRAG);

  const int pre = (ws_size >= (size_t)WS_NEED) ? 1 : 0;

  mmd_pass1<<<dim3(NPTS / 256, 4), 256, 0, stream>>>(src, tgt, sqArr, part1,
                                                     quadbuf, cnt, frags, pre);
  mmd_pass2<<<1, 256, 0, stream>>>(part1, coef);
  if (pre)
    mmd_pass3<true><<<dim3(NPAIR3, 4), 256, 0, stream>>>(src, tgt, sqArr, coef,
                                                         frags, quadbuf, cnt, out);
  else
    mmd_pass3<false><<<dim3(NPAIR3, 4), 256, 0, stream>>>(src, tgt, sqArr, coef,
                                                          frags, quadbuf, cnt, out);
}

// Round 10
// 111.204 us; speedup vs baseline: 1.0328x; 1.0328x over previous
//
#include <hip/hip_runtime.h>
#include <hip/hip_bf16.h>

// MMD-RBF: B=4, Ns=Nt=2048 (N=4096 concat), K=32, KERNEL_MUL=2, KERNEL_NUM=5.
// Pass 1: per-point sq-norms, hi/lo bf16 fragment precompute (if ws fits),
//         per-block partial {sum_sq, comp sums}; zero quadbuf+cnt
// Pass 2: 1 block: reduce partials -> coef[b]
// Pass 3: 528 upper-tri 128x128 tile pairs per batch; fragment panels staged
//         into LDS (slot-XOR swizzle, coalesced copy) -> MFMA hi/lo Gram
//         (fp32 accum) -> fused exp-ladder epilogue; symmetry doubling;
//         completion counter -> last block emits out[b].

#define NPTS 4096   // per batch (2048 src + 2048 tgt)
#define HALF 2048
#define KDIM 32
#define T3   128    // tile dim
#define NTB3 32     // NPTS / T3
#define NPAIR3 528  // NTB3*(NTB3+1)/2
#define SPREAD 64

#define WS_SQ    0          // 4*4096*4  = 65536
#define WS_PART  65536      // 4*16*33*8 = 16896
#define WS_QUAD  82432      // 4*4*64*8  = 8192
#define WS_CNT   90624      // 16
#define WS_COEF  90640      // 16
#define WS_FRAG  98304      // 4*4096*128 = 2 MB
#define WS_NEED  (98304 + 4 * NPTS * 128)

typedef __attribute__((ext_vector_type(8))) short short8v;  // 8 bf16 (4 VGPRs)
typedef __attribute__((ext_vector_type(4))) float f32x4;    // C/D frag

__device__ __forceinline__ float fast_exp2(float x) {
#if __has_builtin(__builtin_amdgcn_exp2f)
  return __builtin_amdgcn_exp2f(x);
#else
  return exp2f(x);
#endif
}

__device__ __forceinline__ unsigned int bf16_rne(float x) {
  unsigned int u = __float_as_uint(x);
  return (u + 0x7fffu + ((u >> 16) & 1u)) >> 16;
}

__device__ __forceinline__ const float* point_ptr(const float* __restrict__ src,
                                                  const float* __restrict__ tgt,
                                                  int b, int p) {
  return (p < HALF) ? src + ((size_t)b * HALF + p) * KDIM
                    : tgt + ((size_t)b * HALF + (p - HALF)) * KDIM;
}

// ---- Pass 1 ----------------------------------------------------------------
__global__ void mmd_pass1(const float* __restrict__ src, const float* __restrict__ tgt,
                          float* __restrict__ sqArr, double* __restrict__ part1,
                          double* __restrict__ quadbuf, unsigned int* __restrict__ cnt,
                          unsigned char* __restrict__ frags, int preFlag) {
  const int b = blockIdx.y;
  const int p = blockIdx.x * 256 + threadIdx.x;

  if (blockIdx.x == 0) {
    quadbuf[b * 4 * SPREAD + threadIdx.x] = 0.0;
    if (threadIdx.x == 0) cnt[b] = 0u;
  }

  const float* __restrict__ xp = point_ptr(src, tgt, b, p);
  float x[KDIM];
#pragma unroll
  for (int q = 0; q < 8; ++q) {
    float4 v = reinterpret_cast<const float4*>(xp)[q];
    x[4*q+0] = v.x; x[4*q+1] = v.y; x[4*q+2] = v.z; x[4*q+3] = v.w;
  }
  float s0 = 0.f, s1 = 0.f, s2 = 0.f, s3 = 0.f;
#pragma unroll
  for (int q = 0; q < 8; ++q) {
    s0 = fmaf(x[4*q+0], x[4*q+0], s0);
    s1 = fmaf(x[4*q+1], x[4*q+1], s1);
    s2 = fmaf(x[4*q+2], x[4*q+2], s2);
    s3 = fmaf(x[4*q+3], x[4*q+3], s3);
  }
  float sq = (s0 + s1) + (s2 + s3);
  sqArr[(size_t)b * NPTS + p] = sq;

  // precompute hi/lo bf16 fragments: 64 B hi (slots 0-3) + 64 B lo (slots 4-7)
  if (preFlag) {
    unsigned int hw[16], lw[16];
#pragma unroll
    for (int e = 0; e < 16; ++e) {
      const float xa = x[2*e], xb = x[2*e+1];
      const unsigned int ha = bf16_rne(xa);
      const unsigned int la = bf16_rne(xa - __uint_as_float(ha << 16));
      const unsigned int hb = bf16_rne(xb);
      const unsigned int lb = bf16_rne(xb - __uint_as_float(hb << 16));
      hw[e] = ha | (hb << 16);
      lw[e] = la | (lb << 16);
    }
    uint4* dst = reinterpret_cast<uint4*>(frags + (size_t)(b * NPTS + p) * 128);
#pragma unroll
    for (int c = 0; c < 4; ++c)
      dst[c] = make_uint4(hw[4*c], hw[4*c+1], hw[4*c+2], hw[4*c+3]);
#pragma unroll
    for (int c = 0; c < 4; ++c)
      dst[4 + c] = make_uint4(lw[4*c], lw[4*c+1], lw[4*c+2], lw[4*c+3]);
  }

  __shared__ float lx[256][KDIM + 1];
  __shared__ float part[8][KDIM];
  __shared__ float sqpart[4];

#pragma unroll
  for (int k = 0; k < KDIM; ++k) lx[threadIdx.x][k] = x[k];

  float w = sq;
#pragma unroll
  for (int off = 32; off > 0; off >>= 1) w += __shfl_down(w, off, 64);
  if ((threadIdx.x & 63) == 0) sqpart[threadIdx.x >> 6] = w;
  __syncthreads();

  const int k = threadIdx.x & 31, g = threadIdx.x >> 5;
  float ps = 0.f;
#pragma unroll 8
  for (int r = 0; r < 32; ++r) ps += lx[g * 32 + r][k];
  part[g][k] = ps;
  __syncthreads();

  double* slot = part1 + ((size_t)b * 16 + blockIdx.x) * 33;
  if (threadIdx.x < 32) {
    float tot = 0.f;
#pragma unroll
    for (int gg = 0; gg < 8; ++gg) tot += part[gg][threadIdx.x];
    slot[1 + threadIdx.x] = (double)tot;
  }
  if (threadIdx.x == 63)
    slot[0] = (double)(sqpart[0] + sqpart[1] + sqpart[2] + sqpart[3]);
}

// ---- Pass 2: 1 block, bandwidth coefficient per batch ----------------------
__global__ void mmd_pass2(const double* __restrict__ part1, float* __restrict__ coef) {
  const int b = threadIdx.x >> 6;   // 4 waves, one per batch
  const int lane = threadIdx.x & 63;
  __shared__ double red[4][33];
  if (lane < 33) {
    double s = 0.0;
    for (int blk = 0; blk < 16; ++blk) s += part1[((size_t)b * 16 + blk) * 33 + lane];
    red[b][lane] = s;
  }
  __syncthreads();
  if (lane == 0) {
    double ssq = red[b][0], s2 = 0.0;
    for (int k = 1; k <= 32; ++k) s2 += red[b][k] * red[b][k];
    const double N = (double)NPTS;
    double bw = (2.0 * N * ssq - 2.0 * s2) / (N * N - N + 1e-8);
    bw *= 0.25;  // / KERNEL_MUL^(KERNEL_NUM//2)
    coef[b] = (float)(-1.4426950408889634 / (bw * 16.0));  // widest bandwidth (t=4)
  }
}

// LDS fragment read: logical slot = half*4 + lk, stored XOR-swizzled by point
__device__ __forceinline__ short8v lds_frag(const unsigned char* base, int p,
                                            int half, int lk) {
  const int slot = (half * 4 + lk) ^ (p & 7);
  return *reinterpret_cast<const short8v*>(base + p * 128 + slot * 16);
}

// ---- Pass 3: LDS-staged MFMA Gram + fused epilogue, upper-tri, sym-doubled -
template <bool PRE>
__global__ void __launch_bounds__(256, 2)
mmd_pass3(const float* __restrict__ src, const float* __restrict__ tgt,
          const float* __restrict__ sqArr, const float* __restrict__ coef,
          const unsigned char* __restrict__ frags,
          double* __restrict__ quadbuf, unsigned int* __restrict__ cnt,
          float* __restrict__ out) {
  const int t = blockIdx.x;            // 0..527 upper-tri pair index
  const int b = blockIdx.y;
  int by = (int)((sqrtf((float)(8 * t + 1)) - 1.0f) * 0.5f);
  while ((by + 1) * (by + 2) / 2 <= t) ++by;
  while (by * (by + 1) / 2 > t) --by;
  const int bx = t - by * (by + 1) / 2;

  const int tid = threadIdx.x;         // 256 = 4 waves
  const int lane = tid & 63;
  const int w = tid >> 6;
  const int lm = lane & 15;            // matrix index within 16
  const int lk = lane >> 4;            // k-group 0..3

  __shared__ __align__(16) unsigned char fragA[T3 * 128];  // 16 KB
  __shared__ __align__(16) unsigned char fragB[T3 * 128];  // 16 KB
  __shared__ float s_sqA[T3], s_sqB[T3];
  __shared__ double wsum[4];
  __shared__ unsigned int s_last;

  const float nc4 = coef[b];
  const float* __restrict__ sqG = sqArr + (size_t)b * NPTS;

  // ---- stage fragment panels into LDS (coalesced, slot-XOR swizzle) ----
  if constexpr (PRE) {
    const uint4* gA = reinterpret_cast<const uint4*>(frags + (size_t)(b * NPTS + bx * T3) * 128);
    const uint4* gB = reinterpret_cast<const uint4*>(frags + (size_t)(b * NPTS + by * T3) * 128);
    uint4* lA = reinterpret_cast<uint4*>(fragA);
    uint4* lB = reinterpret_cast<uint4*>(fragB);
#pragma unroll
    for (int i = 0; i < 4; ++i) {
      const int g = tid + i * 256;      // 0..1023 = point(p)=g>>3, slot(s)=g&7
      const int p = g >> 3, s = g & 7;
      lA[p * 8 + (s ^ (p & 7))] = gA[g];
      lB[p * 8 + (s ^ (p & 7))] = gB[g];
    }
  } else {
    // fallback: build hi/lo inline from fp32 (thread t -> one point)
    const int pt = tid & 127;
    const bool isB = tid >= 128;
    const int gp = (isB ? by : bx) * T3 + pt;
    const float* fp = point_ptr(src, tgt, b, gp);
    unsigned int hw[16], lw[16];
#pragma unroll
    for (int e = 0; e < 16; ++e) {
      const float xa = fp[2*e], xb = fp[2*e+1];
      const unsigned int ha = bf16_rne(xa);
      const unsigned int la = bf16_rne(xa - __uint_as_float(ha << 16));
      const unsigned int hb = bf16_rne(xb);
      const unsigned int lb = bf16_rne(xb - __uint_as_float(hb << 16));
      hw[e] = ha | (hb << 16);
      lw[e] = la | (lb << 16);
    }
    uint4* dst = reinterpret_cast<uint4*>((isB ? fragB : fragA) + pt * 128);
#pragma unroll
    for (int s = 0; s < 8; ++s) {
      const unsigned int* src4 = (s < 4) ? &hw[s * 4] : &lw[(s - 4) * 4];
      dst[s ^ (pt & 7)] = make_uint4(src4[0], src4[1], src4[2], src4[3]);
    }
  }
  if (tid < 128) s_sqA[tid] = sqG[bx * T3 + tid];
  else           s_sqB[tid - 128] = sqG[by * T3 + (tid - 128)];
  __syncthreads();

  // ---- compute: wave owns 64x64 region ----
  const int rbase = (w & 1) * 64;      // local A row base
  const int cbase = (w >> 1) * 64;     // local B col base
  const float m2nc = -2.0f * nc4;

  short8v Bh[4], Bl[4];
  float sjn[4];
#pragma unroll
  for (int cg = 0; cg < 4; ++cg) {
    const int p = cbase + cg * 16 + lm;
    Bh[cg] = lds_frag(fragB, p, 0, lk);
    Bl[cg] = lds_frag(fragB, p, 1, lk);
    sjn[cg] = s_sqB[p] * nc4;
  }

  double accd = 0.0;
#pragma unroll
  for (int rg = 0; rg < 4; ++rg) {
    const int pa = rbase + rg * 16 + lm;
    const short8v Ah = lds_frag(fragA, pa, 0, lk);
    const short8v Al = lds_frag(fragA, pa, 1, lk);
    const float4 sqi4 = *reinterpret_cast<const float4*>(s_sqA + rbase + rg * 16 + lk * 4);
    const float sin_[4] = {sqi4.x * nc4, sqi4.y * nc4, sqi4.z * nc4, sqi4.w * nc4};
#pragma unroll
    for (int cg = 0; cg < 4; ++cg) {
      f32x4 accP = {0.f, 0.f, 0.f, 0.f};
      f32x4 accQ = {0.f, 0.f, 0.f, 0.f};
      accP = __builtin_amdgcn_mfma_f32_16x16x32_bf16(Ah, Bh[cg], accP, 0, 0, 0);
      accQ = __builtin_amdgcn_mfma_f32_16x16x32_bf16(Ah, Bl[cg], accQ, 0, 0, 0);
      accP = __builtin_amdgcn_mfma_f32_16x16x32_bf16(Al, Bl[cg], accP, 0, 0, 0);
      accQ = __builtin_amdgcn_mfma_f32_16x16x32_bf16(Al, Bh[cg], accQ, 0, 0, 0);
      float rs = 0.f;
#pragma unroll
      for (int reg = 0; reg < 4; ++reg) {
        const float dot = accP[reg] + accQ[reg];
        // arg = nc4 * L2 = nc4*(sqi+sqj) - 2*nc4*dot
        const float arg = fmaf(dot, m2nc, sin_[reg] + sjn[cg]);
        float e = fast_exp2(arg);          // widest bandwidth
        float s = e;
        e *= e; s += e;                    // e3
        e *= e; s += e;                    // e2
        e *= e; s += e;                    // e1
        e *= e; s += e;                    // e0
        rs += s;
      }
      accd += (double)rs;
    }
  }

  // block reduce (4 waves) + spread atomics
#pragma unroll
  for (int off = 32; off > 0; off >>= 1) accd += __shfl_down(accd, off, 64);
  if ((tid & 63) == 0) wsum[tid >> 6] = accd;
  __syncthreads();
  if (tid == 0) {
    const double tot = wsum[0] + wsum[1] + wsum[2] + wsum[3];
    const int rh = (bx >= NTB3 / 2) ? 1 : 0;
    const int ch = (by >= NTB3 / 2) ? 1 : 0;
    const int q  = (rh << 1) | ch;
    const int qT = (ch << 1) | rh;
    const int slot = (bx + by * NTB3) & (SPREAD - 1);
    atomicAdd(&quadbuf[(((b << 2) | q) * SPREAD) + slot], tot);
    if (bx != by)
      atomicAdd(&quadbuf[(((b << 2) | qT) * SPREAD) + slot], tot);
    __threadfence();
    s_last = atomicAdd(&cnt[b], 1u);
  }
  __syncthreads();

  // last block of this batch combines the quadrants -> out[b]
  if (s_last == NPAIR3 - 1) {
    const int qq = tid >> 6, i = tid & 63;
    double v = atomicAdd(&quadbuf[((b << 2) | qq) * SPREAD + i], 0.0);
    double sv = (qq == 0 || qq == 3) ? v : -v;
#pragma unroll
    for (int off = 32; off > 0; off >>= 1) sv += __shfl_down(sv, off, 64);
    if ((tid & 63) == 0) wsum[tid >> 6] = sv;
    __syncthreads();
    if (tid == 0) {
      const double inv = 1.0 / ((double)HALF * (double)HALF);
      out[b] = (float)((wsum[0] + wsum[1] + wsum[2] + wsum[3]) * inv);
    }
  }
}

extern "C" void kernel_launch(void* const* d_in, const int* in_sizes, int n_in,
                              void* d_out, int out_size, void* d_ws, size_t ws_size,
                              hipStream_t stream) {
  const float* src = (const float*)d_in[0];
  const float* tgt = (const float*)d_in[1];
  float* out = (float*)d_out;

  char* ws = (char*)d_ws;
  float*         sqArr   = (float*)(ws + WS_SQ);
  double*        part1   = (double*)(ws + WS_PART);
  double*        quadbuf = (double*)(ws + WS_QUAD);
  unsigned int*  cnt     = (unsigned int*)(ws + WS_CNT);
  float*         coef    = (float*)(ws + WS_COEF);
  unsigned char* frags   = (unsigned char*)(ws + WS_FRAG);

  const int pre = (ws_size >= (size_t)WS_NEED) ? 1 : 0;

  mmd_pass1<<<dim3(NPTS / 256, 4), 256, 0, stream>>>(src, tgt, sqArr, part1,
                                                     quadbuf, cnt, frags, pre);
  mmd_pass2<<<1, 256, 0, stream>>>(part1, coef);
  if (pre)
    mmd_pass3<true><<<dim3(NPAIR3, 4), 256, 0, stream>>>(src, tgt, sqArr, coef,
                                                         frags, quadbuf, cnt, out);
  else
    mmd_pass3<false><<<dim3(NPAIR3, 4), 256, 0, stream>>>(src, tgt, sqArr, coef,
                                                          frags, quadbuf, cnt, out);
}

// Round 11
// 95.355 us; speedup vs baseline: 1.2044x; 1.1662x over previous
//
#include <hip/hip_runtime.h>
#include <hip/hip_bf16.h>

// MMD-RBF: B=4, Ns=Nt=2048 (N=4096 concat), K=32, KERNEL_MUL=2, KERNEL_NUM=5.
// Pass 1: per-point sq-norms, hi/lo bf16 fragment precompute; per-block partials;
//         zero quadbuf
// Pass 2: 1 block: reduce partials -> coef[b]
// Pass 3: persistent blocks: 128 blocks/batch x 512 thr (8 waves); each block
//         processes pairs bid, bid+128, ... (4-5 of the 528 upper-tri 128x128
//         pairs) with DOUBLE-BUFFERED LDS fragment panels; MFMA hi/lo Gram;
//         fused exp-ladder epilogue; symmetry doubling; NO fence/counter.
// Pass 4: separate combine kernel (kernel boundary = coherence), out[b].

#define NPTS 4096   // per batch (2048 src + 2048 tgt)
#define HALF 2048
#define KDIM 32
#define T3   128    // tile dim
#define NTB3 32     // NPTS / T3
#define NPAIR3 528  // NTB3*(NTB3+1)/2
#define GRIDX 128   // blocks per batch; pairs pi = bid + it*GRIDX
#define SPREAD 64

#define WS_SQ    0          // 4*4096*4  = 65536
#define WS_PART  65536      // 4*16*33*8 = 16896
#define WS_QUAD  82432      // 4*4*64*8  = 8192
#define WS_COEF  90640      // 16
#define WS_FRAG  98304      // 4*4096*128 = 2 MB
#define WS_NEED  (98304 + 4 * NPTS * 128)

typedef __attribute__((ext_vector_type(8))) short short8v;  // 8 bf16 (4 VGPRs)
typedef __attribute__((ext_vector_type(4))) float f32x4;    // C/D frag

__device__ __forceinline__ float fast_exp2(float x) {
#if __has_builtin(__builtin_amdgcn_exp2f)
  return __builtin_amdgcn_exp2f(x);
#else
  return exp2f(x);
#endif
}

__device__ __forceinline__ unsigned int bf16_rne(float x) {
  unsigned int u = __float_as_uint(x);
  return (u + 0x7fffu + ((u >> 16) & 1u)) >> 16;
}

__device__ __forceinline__ const float* point_ptr(const float* __restrict__ src,
                                                  const float* __restrict__ tgt,
                                                  int b, int p) {
  return (p < HALF) ? src + ((size_t)b * HALF + p) * KDIM
                    : tgt + ((size_t)b * HALF + (p - HALF)) * KDIM;
}

// ---- Pass 1 ----------------------------------------------------------------
__global__ void mmd_pass1(const float* __restrict__ src, const float* __restrict__ tgt,
                          float* __restrict__ sqArr, double* __restrict__ part1,
                          double* __restrict__ quadbuf,
                          unsigned char* __restrict__ frags, int preFlag) {
  const int b = blockIdx.y;
  const int p = blockIdx.x * 256 + threadIdx.x;

  if (blockIdx.x == 0)
    quadbuf[b * 4 * SPREAD + threadIdx.x] = 0.0;

  const float* __restrict__ xp = point_ptr(src, tgt, b, p);
  float x[KDIM];
#pragma unroll
  for (int q = 0; q < 8; ++q) {
    float4 v = reinterpret_cast<const float4*>(xp)[q];
    x[4*q+0] = v.x; x[4*q+1] = v.y; x[4*q+2] = v.z; x[4*q+3] = v.w;
  }
  float s0 = 0.f, s1 = 0.f, s2 = 0.f, s3 = 0.f;
#pragma unroll
  for (int q = 0; q < 8; ++q) {
    s0 = fmaf(x[4*q+0], x[4*q+0], s0);
    s1 = fmaf(x[4*q+1], x[4*q+1], s1);
    s2 = fmaf(x[4*q+2], x[4*q+2], s2);
    s3 = fmaf(x[4*q+3], x[4*q+3], s3);
  }
  float sq = (s0 + s1) + (s2 + s3);
  sqArr[(size_t)b * NPTS + p] = sq;

  // hi/lo bf16 fragments: 64 B hi (slots 0-3) + 64 B lo (slots 4-7) per point
  if (preFlag) {
    unsigned int hw[16], lw[16];
#pragma unroll
    for (int e = 0; e < 16; ++e) {
      const float xa = x[2*e], xb = x[2*e+1];
      const unsigned int ha = bf16_rne(xa);
      const unsigned int la = bf16_rne(xa - __uint_as_float(ha << 16));
      const unsigned int hb = bf16_rne(xb);
      const unsigned int lb = bf16_rne(xb - __uint_as_float(hb << 16));
      hw[e] = ha | (hb << 16);
      lw[e] = la | (lb << 16);
    }
    uint4* dst = reinterpret_cast<uint4*>(frags + (size_t)(b * NPTS + p) * 128);
#pragma unroll
    for (int c = 0; c < 4; ++c)
      dst[c] = make_uint4(hw[4*c], hw[4*c+1], hw[4*c+2], hw[4*c+3]);
#pragma unroll
    for (int c = 0; c < 4; ++c)
      dst[4 + c] = make_uint4(lw[4*c], lw[4*c+1], lw[4*c+2], lw[4*c+3]);
  }

  __shared__ float lx[256][KDIM + 1];
  __shared__ float part[8][KDIM];
  __shared__ float sqpart[4];

#pragma unroll
  for (int k = 0; k < KDIM; ++k) lx[threadIdx.x][k] = x[k];

  float w = sq;
#pragma unroll
  for (int off = 32; off > 0; off >>= 1) w += __shfl_down(w, off, 64);
  if ((threadIdx.x & 63) == 0) sqpart[threadIdx.x >> 6] = w;
  __syncthreads();

  const int k = threadIdx.x & 31, g = threadIdx.x >> 5;
  float ps = 0.f;
#pragma unroll 8
  for (int r = 0; r < 32; ++r) ps += lx[g * 32 + r][k];
  part[g][k] = ps;
  __syncthreads();

  double* slot = part1 + ((size_t)b * 16 + blockIdx.x) * 33;
  if (threadIdx.x < 32) {
    float tot = 0.f;
#pragma unroll
    for (int gg = 0; gg < 8; ++gg) tot += part[gg][threadIdx.x];
    slot[1 + threadIdx.x] = (double)tot;
  }
  if (threadIdx.x == 63)
    slot[0] = (double)(sqpart[0] + sqpart[1] + sqpart[2] + sqpart[3]);
}

// ---- Pass 2: 1 block, bandwidth coefficient per batch ----------------------
__global__ void mmd_pass2(const double* __restrict__ part1, float* __restrict__ coef) {
  const int b = threadIdx.x >> 6;   // 4 waves, one per batch
  const int lane = threadIdx.x & 63;
  __shared__ double red[4][33];
  if (lane < 33) {
    double s = 0.0;
    for (int blk = 0; blk < 16; ++blk) s += part1[((size_t)b * 16 + blk) * 33 + lane];
    red[b][lane] = s;
  }
  __syncthreads();
  if (lane == 0) {
    double ssq = red[b][0], s2 = 0.0;
    for (int k = 1; k <= 32; ++k) s2 += red[b][k] * red[b][k];
    const double N = (double)NPTS;
    double bw = (2.0 * N * ssq - 2.0 * s2) / (N * N - N + 1e-8);
    bw *= 0.25;  // / KERNEL_MUL^(KERNEL_NUM//2)
    coef[b] = (float)(-1.4426950408889634 / (bw * 16.0));  // widest bandwidth (t=4)
  }
}

// LDS fragment read: logical slot = half*4 + lk, stored XOR-swizzled by point
__device__ __forceinline__ short8v lds_frag(const unsigned char* base, int p,
                                            int half, int lk) {
  const int slot = (half * 4 + lk) ^ (p & 7);
  return *reinterpret_cast<const short8v*>(base + p * 128 + slot * 16);
}

// ---- Pass 3: persistent dbuf MFMA Gram + fused epilogue --------------------
template <bool PRE>
__global__ void __launch_bounds__(512, 4)
mmd_pass3(const float* __restrict__ src, const float* __restrict__ tgt,
          const float* __restrict__ sqArr, const float* __restrict__ coef,
          const unsigned char* __restrict__ frags,
          double* __restrict__ quadbuf) {
  const int bid = blockIdx.x;          // 0..127
  const int b = blockIdx.y;
  const int tid = threadIdx.x;         // 512 = 8 waves
  const int lane = tid & 63;
  const int w = tid >> 6;
  const int lm = lane & 15;
  const int lk = lane >> 4;
  const int wr = w & 3;                // wave row-group (32 rows each)
  const int wc = w >> 2;               // wave col-group (64 cols each)

  __shared__ __align__(16) unsigned char fragA[2][T3 * 128];  // 2 x 16 KB
  __shared__ __align__(16) unsigned char fragB[2][T3 * 128];  // 2 x 16 KB
  __shared__ __align__(16) float s_sqA[2][T3];
  __shared__ __align__(16) float s_sqB[2][T3];
  __shared__ double wsum[2][8];

  const float nc4 = coef[b];
  const float m2nc = -2.0f * nc4;
  const float* __restrict__ sqG = sqArr + (size_t)b * NPTS;
  const uint4* __restrict__ gfr =
      reinterpret_cast<const uint4*>(frags) + (size_t)b * NPTS * 8;

  const int npair = (bid + 4 * GRIDX < NPAIR3) ? 5 : 4;

  // decode pair index -> (bx, by), bx <= by
  int bxA[5], byA[5];
#pragma unroll
  for (int it = 0; it < 5; ++it) {
    const int pi = bid + it * GRIDX;
    int y = (int)((sqrtf((float)(8 * pi + 1)) - 1.0f) * 0.5f);
    while ((y + 1) * (y + 2) / 2 <= pi) ++y;
    while (y * (y + 1) / 2 > pi) --y;
    byA[it] = y; bxA[it] = pi - y * (y + 1) / 2;
  }

  // ---- prologue: stage pair 0 into buffer 0 ----
  {
    const int bx = bxA[0], by = byA[0];
    if constexpr (PRE) {
#pragma unroll
      for (int i = 0; i < 2; ++i) {
        const int g = tid + i * 512;       // 0..1023: p = g>>3, s = g&7
        const int p = g >> 3, s = g & 7;
        const int d = p * 8 + (s ^ (p & 7));
        reinterpret_cast<uint4*>(fragA[0])[d] = gfr[(size_t)bx * 1024 + g];
        reinterpret_cast<uint4*>(fragB[0])[d] = gfr[(size_t)by * 1024 + g];
      }
    } else {
      if (tid < 256) {
        const int pt = tid & 127;
        const bool isB = tid >= 128;
        const float* fp = point_ptr(src, tgt, b, (isB ? by : bx) * T3 + pt);
        unsigned int hw[16], lw[16];
#pragma unroll
        for (int e = 0; e < 16; ++e) {
          const float xa = fp[2*e], xb = fp[2*e+1];
          const unsigned int ha = bf16_rne(xa);
          const unsigned int la = bf16_rne(xa - __uint_as_float(ha << 16));
          const unsigned int hb = bf16_rne(xb);
          const unsigned int lb = bf16_rne(xb - __uint_as_float(hb << 16));
          hw[e] = ha | (hb << 16);
          lw[e] = la | (lb << 16);
        }
        uint4* dst = reinterpret_cast<uint4*>((isB ? fragB[0] : fragA[0]) + pt * 128);
#pragma unroll
        for (int s = 0; s < 8; ++s) {
          const unsigned int* s4 = (s < 4) ? &hw[s * 4] : &lw[(s - 4) * 4];
          dst[s ^ (pt & 7)] = make_uint4(s4[0], s4[1], s4[2], s4[3]);
        }
      }
    }
    if (tid < 128) s_sqA[0][tid] = sqG[bx * T3 + tid];
    else if (tid < 256) s_sqB[0][tid - 128] = sqG[by * T3 + (tid - 128)];
  }
  __syncthreads();

  for (int it = 0; it < npair; ++it) {
    const int c = it & 1;
    const int bx = bxA[it], by = byA[it];

    // ---- issue next pair's loads into regs (T14: issue-early/write-late) ----
    uint4 va[2], vb[2];
    float nsqa = 0.f, nsqb = 0.f;
    const bool havenext = (it + 1 < npair);
    if (havenext) {
      const int nbx = bxA[it + 1], nby = byA[it + 1];
      if constexpr (PRE) {
#pragma unroll
        for (int i = 0; i < 2; ++i) {
          const int g = tid + i * 512;
          va[i] = gfr[(size_t)nbx * 1024 + g];
          vb[i] = gfr[(size_t)nby * 1024 + g];
        }
      }
      if (tid < 128) nsqa = sqG[nbx * T3 + tid];
      else if (tid < 256) nsqb = sqG[nby * T3 + (tid - 128)];
    }

    // ---- compute current pair from buffer c ----
    const unsigned char* fA = fragA[c];
    const unsigned char* fB = fragB[c];

    short8v Bh[4], Bl[4];
    float sjn[4];
#pragma unroll
    for (int cg = 0; cg < 4; ++cg) {
      const int p = wc * 64 + cg * 16 + lm;
      Bh[cg] = lds_frag(fB, p, 0, lk);
      Bl[cg] = lds_frag(fB, p, 1, lk);
      sjn[cg] = s_sqB[c][p] * nc4;
    }

    double accd = 0.0;
#pragma unroll
    for (int rg = 0; rg < 2; ++rg) {
      const int pa = wr * 32 + rg * 16 + lm;
      const short8v Ah = lds_frag(fA, pa, 0, lk);
      const short8v Al = lds_frag(fA, pa, 1, lk);
      const float4 sqi4 = *reinterpret_cast<const float4*>(
          &s_sqA[c][wr * 32 + rg * 16 + lk * 4]);
      const float sin_[4] = {sqi4.x * nc4, sqi4.y * nc4, sqi4.z * nc4, sqi4.w * nc4};
#pragma unroll
      for (int cg = 0; cg < 4; ++cg) {
        f32x4 accP = {0.f, 0.f, 0.f, 0.f};
        f32x4 accQ = {0.f, 0.f, 0.f, 0.f};
        accP = __builtin_amdgcn_mfma_f32_16x16x32_bf16(Ah, Bh[cg], accP, 0, 0, 0);
        accQ = __builtin_amdgcn_mfma_f32_16x16x32_bf16(Ah, Bl[cg], accQ, 0, 0, 0);
        accP = __builtin_amdgcn_mfma_f32_16x16x32_bf16(Al, Bl[cg], accP, 0, 0, 0);
        accQ = __builtin_amdgcn_mfma_f32_16x16x32_bf16(Al, Bh[cg], accQ, 0, 0, 0);
        float rs = 0.f;
#pragma unroll
        for (int reg = 0; reg < 4; ++reg) {
          const float dot = accP[reg] + accQ[reg];
          const float arg = fmaf(dot, m2nc, sin_[reg] + sjn[cg]);
          float e = fast_exp2(arg);          // widest bandwidth
          float s = e;
          e *= e; s += e;                    // e3
          e *= e; s += e;                    // e2
          e *= e; s += e;                    // e1
          e *= e; s += e;                    // e0
          rs += s;
        }
        accd += (double)rs;
      }
    }

    // wave reduce -> wsum[c][w]
#pragma unroll
    for (int off = 32; off > 0; off >>= 1) accd += __shfl_down(accd, off, 64);
    if (lane == 0) wsum[c][w] = accd;

    // ---- write next pair's panels into buffer c^1 (before the barrier) ----
    if (havenext) {
      if constexpr (PRE) {
#pragma unroll
        for (int i = 0; i < 2; ++i) {
          const int g = tid + i * 512;
          const int p = g >> 3, s = g & 7;
          const int d = p * 8 + (s ^ (p & 7));
          reinterpret_cast<uint4*>(fragA[c ^ 1])[d] = va[i];
          reinterpret_cast<uint4*>(fragB[c ^ 1])[d] = vb[i];
        }
      } else {
        const int nbx = bxA[it + 1], nby = byA[it + 1];
        if (tid < 256) {
          const int pt = tid & 127;
          const bool isB = tid >= 128;
          const float* fp = point_ptr(src, tgt, b, (isB ? nby : nbx) * T3 + pt);
          unsigned int hw[16], lw[16];
#pragma unroll
          for (int e = 0; e < 16; ++e) {
            const float xa = fp[2*e], xb = fp[2*e+1];
            const unsigned int ha = bf16_rne(xa);
            const unsigned int la = bf16_rne(xa - __uint_as_float(ha << 16));
            const unsigned int hb = bf16_rne(xb);
            const unsigned int lb = bf16_rne(xb - __uint_as_float(hb << 16));
            hw[e] = ha | (hb << 16);
            lw[e] = la | (lb << 16);
          }
          uint4* dst = reinterpret_cast<uint4*>(
              (isB ? fragB[c ^ 1] : fragA[c ^ 1]) + pt * 128);
#pragma unroll
          for (int s = 0; s < 8; ++s) {
            const unsigned int* s4 = (s < 4) ? &hw[s * 4] : &lw[(s - 4) * 4];
            dst[s ^ (pt & 7)] = make_uint4(s4[0], s4[1], s4[2], s4[3]);
          }
        }
      }
      if (tid < 128) s_sqA[c ^ 1][tid] = nsqa;
      else if (tid < 256) s_sqB[c ^ 1][tid - 128] = nsqb;
    }

    __syncthreads();   // next buffer staged AND wsum[c] complete

    if (tid == 0) {
      double tot = 0.0;
#pragma unroll
      for (int ww = 0; ww < 8; ++ww) tot += wsum[c][ww];
      const int rh = (bx >= NTB3 / 2) ? 1 : 0;
      const int ch = (by >= NTB3 / 2) ? 1 : 0;
      const int q  = (rh << 1) | ch;
      const int qT = (ch << 1) | rh;
      const int slot = (bx + by * NTB3) & (SPREAD - 1);
      atomicAdd(&quadbuf[(((b << 2) | q) * SPREAD) + slot], tot);
      if (bx != by)
        atomicAdd(&quadbuf[(((b << 2) | qT) * SPREAD) + slot], tot);
    }
  }
}

// ---- Pass 4: final combine (kernel boundary gives coherence) ---------------
__global__ void mmd_pass4(const double* __restrict__ quadbuf, float* __restrict__ out) {
  const int tid = threadIdx.x;  // 256
  const int qq = tid >> 6, i = tid & 63;
  __shared__ double wsum[4];
  const double inv = 1.0 / ((double)HALF * (double)HALF);
  for (int b = 0; b < 4; ++b) {
    double v = quadbuf[((b << 2) | qq) * SPREAD + i];
    double sv = (qq == 0 || qq == 3) ? v : -v;
#pragma unroll
    for (int off = 32; off > 0; off >>= 1) sv += __shfl_down(sv, off, 64);
    if ((tid & 63) == 0) wsum[qq] = sv;
    __syncthreads();
    if (tid == 0) out[b] = (float)((wsum[0] + wsum[1] + wsum[2] + wsum[3]) * inv);
    __syncthreads();
  }
}

extern "C" void kernel_launch(void* const* d_in, const int* in_sizes, int n_in,
                              void* d_out, int out_size, void* d_ws, size_t ws_size,
                              hipStream_t stream) {
  const float* src = (const float*)d_in[0];
  const float* tgt = (const float*)d_in[1];
  float* out = (float*)d_out;

  char* ws = (char*)d_ws;
  float*         sqArr   = (float*)(ws + WS_SQ);
  double*        part1   = (double*)(ws + WS_PART);
  double*        quadbuf = (double*)(ws + WS_QUAD);
  float*         coef    = (float*)(ws + WS_COEF);
  unsigned char* frags   = (unsigned char*)(ws + WS_FRAG);

  const int pre = (ws_size >= (size_t)WS_NEED) ? 1 : 0;

  mmd_pass1<<<dim3(NPTS / 256, 4), 256, 0, stream>>>(src, tgt, sqArr, part1,
                                                     quadbuf, frags, pre);
  mmd_pass2<<<1, 256, 0, stream>>>(part1, coef);
  if (pre)
    mmd_pass3<true><<<dim3(GRIDX, 4), 512, 0, stream>>>(src, tgt, sqArr, coef,
                                                        frags, quadbuf);
  else
    mmd_pass3<false><<<dim3(GRIDX, 4), 512, 0, stream>>>(src, tgt, sqArr, coef,
                                                         frags, quadbuf);
  mmd_pass4<<<1, 256, 0, stream>>>(quadbuf, out);
}

// Round 12
// 83.745 us; speedup vs baseline: 1.3714x; 1.1386x over previous
//
#include <hip/hip_runtime.h>
#include <hip/hip_bf16.h>

// MMD-RBF: B=4, Ns=Nt=2048 (N=4096 concat), K=32, KERNEL_MUL=2, KERNEL_NUM=5.
// Pass 1: 256 one-wave blocks: per-point sq-norms + hi/lo bf16 frag precompute
//         + per-block partial {sum_sq, comp sums}; zero quadbuf
// Pass 3: grid (176,4) x 512 thr, 3 pairs/block exactly; single-buffer LDS
//         fragment panels (34 KB -> 3 blocks/CU @ launch_bounds(512,6));
//         per-block coef reduce in prologue (pass2 merged); cg-outer MFMA
//         hi/lo Gram; fused exp-ladder epilogue; symmetry doubling.
// Pass 4: separate combine kernel (kernel boundary = coherence), out[b].

#define NPTS 4096   // per batch (2048 src + 2048 tgt)
#define HALF 2048
#define KDIM 32
#define T3   128    // tile dim
#define NTB3 32     // NPTS / T3
#define NPAIR3 528  // NTB3*(NTB3+1)/2
#define GRIDX 176   // blocks per batch; pairs pi = bid + it*GRIDX, it<3
#define SPREAD 64

#define WS_SQ    0          // 4*4096*4   = 65536
#define WS_PART  65536      // 4*64*33*8  = 67584  -> ends 133120
#define WS_QUAD  133120     // 4*4*64*8   = 8192   -> ends 141312
#define WS_FRAG  147456     // 4*4096*128 = 2 MB
#define WS_NEED  (147456 + 4 * NPTS * 128)

typedef __attribute__((ext_vector_type(8))) short short8v;  // 8 bf16 (4 VGPRs)
typedef __attribute__((ext_vector_type(4))) float f32x4;    // C/D frag

__device__ __forceinline__ float fast_exp2(float x) {
#if __has_builtin(__builtin_amdgcn_exp2f)
  return __builtin_amdgcn_exp2f(x);
#else
  return exp2f(x);
#endif
}

__device__ __forceinline__ unsigned int bf16_rne(float x) {
  unsigned int u = __float_as_uint(x);
  return (u + 0x7fffu + ((u >> 16) & 1u)) >> 16;
}

__device__ __forceinline__ const float* point_ptr(const float* __restrict__ src,
                                                  const float* __restrict__ tgt,
                                                  int b, int p) {
  return (p < HALF) ? src + ((size_t)b * HALF + p) * KDIM
                    : tgt + ((size_t)b * HALF + (p - HALF)) * KDIM;
}

// ---- Pass 1: 64-thread blocks, grid (64, 4) --------------------------------
__global__ void __launch_bounds__(64)
mmd_pass1(const float* __restrict__ src, const float* __restrict__ tgt,
          float* __restrict__ sqArr, double* __restrict__ part1,
          double* __restrict__ quadbuf,
          unsigned char* __restrict__ frags, int preFlag) {
  const int b = blockIdx.y;
  const int tid = threadIdx.x;       // 0..63
  const int p = blockIdx.x * 64 + tid;

  if (blockIdx.x == 0) {
#pragma unroll
    for (int i = 0; i < 4; ++i)
      quadbuf[b * 4 * SPREAD + i * 64 + tid] = 0.0;
  }

  const float* __restrict__ xp = point_ptr(src, tgt, b, p);
  float x[KDIM];
#pragma unroll
  for (int q = 0; q < 8; ++q) {
    float4 v = reinterpret_cast<const float4*>(xp)[q];
    x[4*q+0] = v.x; x[4*q+1] = v.y; x[4*q+2] = v.z; x[4*q+3] = v.w;
  }
  float s0 = 0.f, s1 = 0.f, s2 = 0.f, s3 = 0.f;
#pragma unroll
  for (int q = 0; q < 8; ++q) {
    s0 = fmaf(x[4*q+0], x[4*q+0], s0);
    s1 = fmaf(x[4*q+1], x[4*q+1], s1);
    s2 = fmaf(x[4*q+2], x[4*q+2], s2);
    s3 = fmaf(x[4*q+3], x[4*q+3], s3);
  }
  const float sq = (s0 + s1) + (s2 + s3);
  sqArr[(size_t)b * NPTS + p] = sq;

  // hi/lo bf16 fragments: 64 B hi (slots 0-3) + 64 B lo (slots 4-7) per point
  if (preFlag) {
    unsigned int hw[16], lw[16];
#pragma unroll
    for (int e = 0; e < 16; ++e) {
      const float xa = x[2*e], xb = x[2*e+1];
      const unsigned int ha = bf16_rne(xa);
      const unsigned int la = bf16_rne(xa - __uint_as_float(ha << 16));
      const unsigned int hb = bf16_rne(xb);
      const unsigned int lb = bf16_rne(xb - __uint_as_float(hb << 16));
      hw[e] = ha | (hb << 16);
      lw[e] = la | (lb << 16);
    }
    uint4* dst = reinterpret_cast<uint4*>(frags + (size_t)(b * NPTS + p) * 128);
#pragma unroll
    for (int c = 0; c < 4; ++c)
      dst[c] = make_uint4(hw[4*c], hw[4*c+1], hw[4*c+2], hw[4*c+3]);
#pragma unroll
    for (int c = 0; c < 4; ++c)
      dst[4 + c] = make_uint4(lw[4*c], lw[4*c+1], lw[4*c+2], lw[4*c+3]);
  }

  // component sums via LDS transpose (one wave)
  __shared__ float lx[64][KDIM + 1];
#pragma unroll
  for (int k = 0; k < KDIM; ++k) lx[tid][k] = x[k];
  __syncthreads();

  double* slot = part1 + ((size_t)b * 64 + blockIdx.x) * 33;
  if (tid < 32) {
    float ps = 0.f;
#pragma unroll 16
    for (int r = 0; r < 64; ++r) ps += lx[r][tid];
    slot[1 + tid] = (double)ps;
  }
  float w = sq;
#pragma unroll
  for (int off = 32; off > 0; off >>= 1) w += __shfl_down(w, off, 64);
  if (tid == 0) slot[0] = (double)w;
}

// LDS fragment read: logical slot = half*4 + lk, stored XOR-swizzled by point
__device__ __forceinline__ short8v lds_frag(const unsigned char* base, int p,
                                            int half, int lk) {
  const int slot = (half * 4 + lk) ^ (p & 7);
  return *reinterpret_cast<const short8v*>(base + p * 128 + slot * 16);
}

// ---- Pass 3: single-buffer persistent MFMA Gram + fused epilogue -----------
template <bool PRE>
__global__ void __launch_bounds__(512, 6)
mmd_pass3(const float* __restrict__ src, const float* __restrict__ tgt,
          const float* __restrict__ sqArr, const double* __restrict__ part1,
          const unsigned char* __restrict__ frags,
          double* __restrict__ quadbuf) {
  const int bid = blockIdx.x;          // 0..175
  const int b = blockIdx.y;
  const int tid = threadIdx.x;         // 512 = 8 waves
  const int lane = tid & 63;
  const int w = tid >> 6;
  const int lm = lane & 15;
  const int lk = lane >> 4;
  const int wr = w & 3;                // wave row-group (32 rows)
  const int wc = w >> 2;               // wave col-group (64 cols)

  __shared__ __align__(16) unsigned char fragA[T3 * 128];  // 16 KB
  __shared__ __align__(16) unsigned char fragB[T3 * 128];  // 16 KB
  __shared__ float s_sqA[T3], s_sqB[T3];
  __shared__ double red[33];
  __shared__ float s_nc4;
  __shared__ double wsum[8];

  const float* __restrict__ sqG = sqArr + (size_t)b * NPTS;
  const uint4* __restrict__ gfr =
      reinterpret_cast<const uint4*>(frags) + (size_t)b * NPTS * 8;

  // ---- merged pass2: bandwidth coefficient (redundant per block) ----
  if (tid < 33) {
    double s = 0.0;
#pragma unroll 16
    for (int blk = 0; blk < 64; ++blk)
      s += part1[((size_t)b * 64 + blk) * 33 + tid];
    red[tid] = s;
  }
  __syncthreads();
  if (tid == 0) {
    double ssq = red[0], s2 = 0.0;
    for (int k = 1; k <= 32; ++k) s2 += red[k] * red[k];
    const double N = (double)NPTS;
    double bw = (2.0 * N * ssq - 2.0 * s2) / (N * N - N + 1e-8);
    bw *= 0.25;  // / KERNEL_MUL^(KERNEL_NUM//2)
    s_nc4 = (float)(-1.4426950408889634 / (bw * 16.0));  // widest bandwidth (t=4)
  }

  // decode 3 pairs (bx <= by)
  int bxA[3], byA[3];
#pragma unroll
  for (int it = 0; it < 3; ++it) {
    const int pi = bid + it * GRIDX;
    int y = (int)((sqrtf((float)(8 * pi + 1)) - 1.0f) * 0.5f);
    while ((y + 1) * (y + 2) / 2 <= pi) ++y;
    while (y * (y + 1) / 2 > pi) --y;
    byA[it] = y; bxA[it] = pi - y * (y + 1) / 2;
  }

  // ---- stage pair 0 ----
  {
    const int bx = bxA[0], by = byA[0];
    if constexpr (PRE) {
#pragma unroll
      for (int i = 0; i < 2; ++i) {
        const int g = tid + i * 512;       // p = g>>3, s = g&7
        const int p = g >> 3, s = g & 7;
        const int d = p * 8 + (s ^ (p & 7));
        reinterpret_cast<uint4*>(fragA)[d] = gfr[(size_t)bx * 1024 + g];
        reinterpret_cast<uint4*>(fragB)[d] = gfr[(size_t)by * 1024 + g];
      }
    } else if (tid < 256) {
      const int pt = tid & 127;
      const bool isB = tid >= 128;
      const float* fp = point_ptr(src, tgt, b, (isB ? by : bx) * T3 + pt);
      unsigned int hw[16], lw[16];
#pragma unroll
      for (int e = 0; e < 16; ++e) {
        const float xa = fp[2*e], xb = fp[2*e+1];
        const unsigned int ha = bf16_rne(xa);
        const unsigned int la = bf16_rne(xa - __uint_as_float(ha << 16));
        const unsigned int hb = bf16_rne(xb);
        const unsigned int lb = bf16_rne(xb - __uint_as_float(hb << 16));
        hw[e] = ha | (hb << 16);
        lw[e] = la | (lb << 16);
      }
      uint4* dst = reinterpret_cast<uint4*>((isB ? fragB : fragA) + pt * 128);
#pragma unroll
      for (int s = 0; s < 8; ++s) {
        const unsigned int* s4 = (s < 4) ? &hw[s * 4] : &lw[(s - 4) * 4];
        dst[s ^ (pt & 7)] = make_uint4(s4[0], s4[1], s4[2], s4[3]);
      }
    }
    if (tid < 128) s_sqA[tid] = sqG[bx * T3 + tid];
    else if (tid < 256) s_sqB[tid - 128] = sqG[by * T3 + (tid - 128)];
  }
  __syncthreads();   // buf + s_nc4 visible

  const float nc4 = s_nc4;
  const float m2nc = -2.0f * nc4;

  for (int it = 0; it < 3; ++it) {
    const int bx = bxA[it], by = byA[it];

    // ---- compute current pair (cg outer: only 1 B-frag pair resident) ----
    double accd = 0.0;
#pragma unroll
    for (int cg = 0; cg < 4; ++cg) {
      const int pb = wc * 64 + cg * 16 + lm;
      const short8v Bh = lds_frag(fragB, pb, 0, lk);
      const short8v Bl = lds_frag(fragB, pb, 1, lk);
      const float sjn = s_sqB[pb] * nc4;
#pragma unroll
      for (int rg = 0; rg < 2; ++rg) {
        const int pa = wr * 32 + rg * 16 + lm;
        const short8v Ah = lds_frag(fragA, pa, 0, lk);
        const short8v Al = lds_frag(fragA, pa, 1, lk);
        const float4 sqi4 = *reinterpret_cast<const float4*>(
            &s_sqA[wr * 32 + rg * 16 + lk * 4]);
        const float sin_[4] = {sqi4.x * nc4, sqi4.y * nc4,
                               sqi4.z * nc4, sqi4.w * nc4};
        f32x4 accP = {0.f, 0.f, 0.f, 0.f};
        f32x4 accQ = {0.f, 0.f, 0.f, 0.f};
        accP = __builtin_amdgcn_mfma_f32_16x16x32_bf16(Ah, Bh, accP, 0, 0, 0);
        accQ = __builtin_amdgcn_mfma_f32_16x16x32_bf16(Ah, Bl, accQ, 0, 0, 0);
        accP = __builtin_amdgcn_mfma_f32_16x16x32_bf16(Al, Bl, accP, 0, 0, 0);
        accQ = __builtin_amdgcn_mfma_f32_16x16x32_bf16(Al, Bh, accQ, 0, 0, 0);
        float rs = 0.f;
#pragma unroll
        for (int reg = 0; reg < 4; ++reg) {
          const float dot = accP[reg] + accQ[reg];
          const float arg = fmaf(dot, m2nc, sin_[reg] + sjn);
          float e = fast_exp2(arg);          // widest bandwidth
          float s = e;
          e *= e; s += e;                    // e3
          e *= e; s += e;                    // e2
          e *= e; s += e;                    // e1
          e *= e; s += e;                    // e0
          rs += s;
        }
        accd += (double)rs;
      }
    }

    // wave reduce -> wsum[w]
#pragma unroll
    for (int off = 32; off > 0; off >>= 1) accd += __shfl_down(accd, off, 64);
    if (lane == 0) wsum[w] = accd;

    __syncthreads();   // all done reading buf; wsum ready

    if (tid == 0) {
      double tot = 0.0;
#pragma unroll
      for (int ww = 0; ww < 8; ++ww) tot += wsum[ww];
      const int rh = (bx >= NTB3 / 2) ? 1 : 0;
      const int ch = (by >= NTB3 / 2) ? 1 : 0;
      const int q  = (rh << 1) | ch;
      const int qT = (ch << 1) | rh;
      const int slot = (bx + by * NTB3) & (SPREAD - 1);
      atomicAdd(&quadbuf[(((b << 2) | q) * SPREAD) + slot], tot);
      if (bx != by)
        atomicAdd(&quadbuf[(((b << 2) | qT) * SPREAD) + slot], tot);
    }

    // ---- stage next pair (overlaps tid0's atomics) ----
    if (it + 1 < 3) {
      const int nbx = bxA[it + 1], nby = byA[it + 1];
      if constexpr (PRE) {
#pragma unroll
        for (int i = 0; i < 2; ++i) {
          const int g = tid + i * 512;
          const int p = g >> 3, s = g & 7;
          const int d = p * 8 + (s ^ (p & 7));
          reinterpret_cast<uint4*>(fragA)[d] = gfr[(size_t)nbx * 1024 + g];
          reinterpret_cast<uint4*>(fragB)[d] = gfr[(size_t)nby * 1024 + g];
        }
      } else if (tid < 256) {
        const int pt = tid & 127;
        const bool isB = tid >= 128;
        const float* fp = point_ptr(src, tgt, b, (isB ? nby : nbx) * T3 + pt);
        unsigned int hw[16], lw[16];
#pragma unroll
        for (int e = 0; e < 16; ++e) {
          const float xa = fp[2*e], xb = fp[2*e+1];
          const unsigned int ha = bf16_rne(xa);
          const unsigned int la = bf16_rne(xa - __uint_as_float(ha << 16));
          const unsigned int hb = bf16_rne(xb);
          const unsigned int lb = bf16_rne(xb - __uint_as_float(hb << 16));
          hw[e] = ha | (hb << 16);
          lw[e] = la | (lb << 16);
        }
        uint4* dst = reinterpret_cast<uint4*>((isB ? fragB : fragA) + pt * 128);
#pragma unroll
        for (int s = 0; s < 8; ++s) {
          const unsigned int* s4 = (s < 4) ? &hw[s * 4] : &lw[(s - 4) * 4];
          dst[s ^ (pt & 7)] = make_uint4(s4[0], s4[1], s4[2], s4[3]);
        }
      }
      if (tid < 128) s_sqA[tid] = sqG[nbx * T3 + tid];
      else if (tid < 256) s_sqB[tid - 128] = sqG[nby * T3 + (tid - 128)];
      __syncthreads();   // next buf ready
    }
  }
}

// ---- Pass 4: final combine (kernel boundary gives coherence) ---------------
__global__ void mmd_pass4(const double* __restrict__ quadbuf, float* __restrict__ out) {
  const int tid = threadIdx.x;  // 256
  const int qq = tid >> 6, i = tid & 63;
  __shared__ double wsum[4];
  const double inv = 1.0 / ((double)HALF * (double)HALF);
  for (int b = 0; b < 4; ++b) {
    double v = quadbuf[((b << 2) | qq) * SPREAD + i];
    double sv = (qq == 0 || qq == 3) ? v : -v;
#pragma unroll
    for (int off = 32; off > 0; off >>= 1) sv += __shfl_down(sv, off, 64);
    if ((tid & 63) == 0) wsum[qq] = sv;
    __syncthreads();
    if (tid == 0) out[b] = (float)((wsum[0] + wsum[1] + wsum[2] + wsum[3]) * inv);
    __syncthreads();
  }
}

extern "C" void kernel_launch(void* const* d_in, const int* in_sizes, int n_in,
                              void* d_out, int out_size, void* d_ws, size_t ws_size,
                              hipStream_t stream) {
  const float* src = (const float*)d_in[0];
  const float* tgt = (const float*)d_in[1];
  float* out = (float*)d_out;

  char* ws = (char*)d_ws;
  float*         sqArr   = (float*)(ws + WS_SQ);
  double*        part1   = (double*)(ws + WS_PART);
  double*        quadbuf = (double*)(ws + WS_QUAD);
  unsigned char* frags   = (unsigned char*)(ws + WS_FRAG);

  const int pre = (ws_size >= (size_t)WS_NEED) ? 1 : 0;

  mmd_pass1<<<dim3(64, 4), 64, 0, stream>>>(src, tgt, sqArr, part1,
                                            quadbuf, frags, pre);
  if (pre)
    mmd_pass3<true><<<dim3(GRIDX, 4), 512, 0, stream>>>(src, tgt, sqArr, part1,
                                                        frags, quadbuf);
  else
    mmd_pass3<false><<<dim3(GRIDX, 4), 512, 0, stream>>>(src, tgt, sqArr, part1,
                                                         frags, quadbuf);
  mmd_pass4<<<1, 256, 0, stream>>>(quadbuf, out);
}